// Round 11
// baseline (158.346 us; speedup 1.0000x reference)
//
#include <hip/hip_runtime.h>
#include <hip/hip_bf16.h>

#define B_SZ   4
#define DEC_SZ 128
#define ENC_SZ 512
#define H_SZ   768
#define OUT_N  (B_SZ * DEC_SZ * ENC_SZ)

typedef __attribute__((ext_vector_type(8))) short s8v;   // 8 bf16 (4 VGPRs)
typedef __attribute__((ext_vector_type(4))) float fvec4; // MFMA accumulator
typedef __attribute__((ext_vector_type(4))) float f4r;   // raw float4
typedef __attribute__((address_space(4))) const f4r cf4; // constant-AS float4 -> s_load

// fp32 -> bf16, round-to-nearest-even
__device__ inline unsigned short f2bf(float x) {
  union { float f; unsigned u; } v; v.f = x;
  unsigned r = v.u + 0x7FFF + ((v.u >> 16) & 1);
  return (unsigned short)(r >> 16);
}

// load 8 k-contiguous elements as bf16x8 (converting if fp32 source)
__device__ inline s8v load8(const unsigned short* p) { return *(const s8v*)p; }
__device__ inline s8v load8(const float* p) {
  float4 a = ((const float4*)p)[0];
  float4 b = ((const float4*)p)[1];
  unsigned short r[8] = {f2bf(a.x), f2bf(a.y), f2bf(a.z), f2bf(a.w),
                         f2bf(b.x), f2bf(b.y), f2bf(b.z), f2bf(b.w)};
  return *(const s8v*)r;
}

// ---------------------------------------------------------------------------
// Prep: transpose W (768x768 fp32, (k,n)) -> WT bf16 (n,k). z selects W1/W2.
// ---------------------------------------------------------------------------
__global__ __launch_bounds__(256) void transpose_w(const float* __restrict__ W1,
                                                   const float* __restrict__ W2,
                                                   unsigned short* __restrict__ T1,
                                                   unsigned short* __restrict__ T2) {
  const float* W = blockIdx.z ? W2 : W1;
  unsigned short* T = blockIdx.z ? T2 : T1;
  __shared__ float tile[64][65];
  int c0 = blockIdx.x * 64;
  int r0 = blockIdx.y * 64;
  int tx = threadIdx.x & 63, ty = threadIdx.x >> 6;
#pragma unroll
  for (int i = 0; i < 16; ++i) {
    int r = ty + i * 4;
    tile[r][tx] = W[(size_t)(r0 + r) * H_SZ + c0 + tx];
  }
  __syncthreads();
#pragma unroll
  for (int i = 0; i < 16; ++i) {
    int c = ty + i * 4;
    T[(size_t)(c0 + c) * H_SZ + r0 + tx] = f2bf(tile[tx][c]);
  }
}

// ---------------------------------------------------------------------------
// MFMA NT GEMM body + exp2 epilogue, register-prefetch double-buffered.
// E[m][n] = exp2(C2 * sum_k A[m][k]*B[n][k]); A,B k-contiguous rows (len H).
// Tile 128x64, BK=32, 4 waves; fp32 operands converted to bf16 during staging.
// TILED: m = h, n = (b*ENC+e); float4 store to pe tile layout
//        ((b*8 + e/64)*192 + h/4)*64 + (e&63), component h&3.
// ---------------------------------------------------------------------------
template <bool TILED, typename TA, typename TB>
__device__ inline void gemm_body(const TA* __restrict__ A, const TB* __restrict__ B,
                                 float* __restrict__ C, int ldc, int bx, int by) {
  const int m0 = bx * 128;
  const int n0 = by * 64;

  __shared__ unsigned short As[128][40];  // pad 40: 80 B rows
  __shared__ unsigned short Bs[64][40];

  const int tid  = threadIdx.x;
  const int wave = tid >> 6;
  const int lane = tid & 63;
  const int l16  = lane & 15;
  const int quad = lane >> 4;
  const int wm   = wave * 32;

  int ar[2], ak[2];
#pragma unroll
  for (int i = 0; i < 2; ++i) {
    int seg = tid + 256 * i;
    ar[i] = seg >> 2; ak[i] = (seg & 3) * 8;
  }
  const int br = tid >> 2, bk = (tid & 3) * 8;

  fvec4 acc[2][4];
#pragma unroll
  for (int i = 0; i < 2; ++i)
#pragma unroll
    for (int j = 0; j < 4; ++j) acc[i][j] = (fvec4)0.f;

  s8v pa[2], pb;
#pragma unroll
  for (int i = 0; i < 2; ++i) pa[i] = load8(A + (size_t)(m0 + ar[i]) * H_SZ + ak[i]);
  pb = load8(B + (size_t)(n0 + br) * H_SZ + bk);

  for (int k0 = 0; k0 < H_SZ; k0 += 32) {
    __syncthreads();
#pragma unroll
    for (int i = 0; i < 2; ++i) *(s8v*)&As[ar[i]][ak[i]] = pa[i];
    *(s8v*)&Bs[br][bk] = pb;
    __syncthreads();

    if (k0 + 32 < H_SZ) {
#pragma unroll
      for (int i = 0; i < 2; ++i)
        pa[i] = load8(A + (size_t)(m0 + ar[i]) * H_SZ + k0 + 32 + ak[i]);
      pb = load8(B + (size_t)(n0 + br) * H_SZ + k0 + 32 + bk);
    }

    s8v af[2], bf[4];
#pragma unroll
    for (int i = 0; i < 2; ++i) af[i] = *(const s8v*)&As[wm + i * 16 + l16][quad * 8];
#pragma unroll
    for (int j = 0; j < 4; ++j) bf[j] = *(const s8v*)&Bs[j * 16 + l16][quad * 8];
#pragma unroll
    for (int i = 0; i < 2; ++i)
#pragma unroll
      for (int j = 0; j < 4; ++j)
        acc[i][j] = __builtin_amdgcn_mfma_f32_16x16x32_bf16(af[i], bf[j], acc[i][j], 0, 0, 0);
  }

  const float C2 = 2.885390082f;  // 2 * log2(e)
#pragma unroll
  for (int i = 0; i < 2; ++i) {
    int mbase = m0 + wm + i * 16 + quad * 4;  // C/D: row = quad*4 + reg, col = l16
#pragma unroll
    for (int j = 0; j < 4; ++j) {
      int n = n0 + j * 16 + l16;
      if (TILED) {
        float4 o;
        o.x = __builtin_amdgcn_exp2f(acc[i][j][0] * C2);
        o.y = __builtin_amdgcn_exp2f(acc[i][j][1] * C2);
        o.z = __builtin_amdgcn_exp2f(acc[i][j][2] * C2);
        o.w = __builtin_amdgcn_exp2f(acc[i][j][3] * C2);
        int bIdx = n >> 9, es = (n >> 6) & 7, el = n & 63;
        ((float4*)C)[((size_t)(bIdx * 8 + es) * 192 + (mbase >> 2)) * 64 + el] = o;
      } else {
#pragma unroll
        for (int r = 0; r < 4; ++r)
          C[(size_t)(mbase + r) * ldc + n] = __builtin_amdgcn_exp2f(acc[i][j][r] * C2);
      }
    }
  }
}

// Both GEMMs in one launch: blocks 0..191 -> pe GEMM, 192..239 -> pd GEMM.
__global__ __launch_bounds__(256) void gemm_both(const unsigned short* __restrict__ W1T,
                                                 const float* __restrict__ enc,
                                                 const float* __restrict__ dec,
                                                 const unsigned short* __restrict__ W2T,
                                                 float* __restrict__ peT,
                                                 float* __restrict__ pdm) {
  int bid = blockIdx.x;
  if (bid < 192) {
    gemm_body<true>(W1T, enc, peT, 0, bid % 6, bid / 6);
  } else {
    int r = bid - 192;
    gemm_body<false>(dec, W2T, pdm, H_SZ, r % 4, r / 4);
  }
}

// ---------------------------------------------------------------------------
// Fused score + mask + outputs. Quad-rcp batching (14 VALU + 1 rcp per 4 k)
// with: (a) vt/pd loads through constant address space -> s_load_dwordx4,
// (b) 2 d's per wave (pe element reused, VMEM+addr amortized), k quartered.
// Block 512 thr = 8 waves: wave = dpair(2) x kq(4); 48 quads per wave.
// 4-way k-reduce via LDS. Grid 1024 XCD-swizzled blocks -> 32 waves/CU.
// pe layout: float4[(b*8+es)*192 + k/4][64lane].
// ---------------------------------------------------------------------------
__device__ inline float quad_acc(f4r cur, f4r p4, f4r v4, float t) {
  float a  = fmaf(cur.x, p4.x, 1.f);
  float bq = fmaf(cur.y, p4.y, 1.f);
  float cq = fmaf(cur.z, p4.z, 1.f);
  float dq = fmaf(cur.w, p4.w, 1.f);
  float ab = a * bq, cd = cq * dq;
  float n01 = fmaf(v4.x, bq, v4.y * a);
  float n23 = fmaf(v4.z, dq, v4.w * cq);
  float num = fmaf(n23, ab, n01 * cd);
  return fmaf(num, __builtin_amdgcn_rcpf(ab * cd), t);
}

__global__ __launch_bounds__(512) void score_out(const float* __restrict__ peT,
                                                 const float* __restrict__ pdm,
                                                 const float* __restrict__ vt,
                                                 const float* __restrict__ mask,
                                                 float* __restrict__ out) {
  const int tid   = threadIdx.x;
  const int lane  = tid & 63;
  const int wave  = __builtin_amdgcn_readfirstlane(tid >> 6);
  const int dpair = wave & 1;    // which pair of d's
  const int kq    = wave >> 1;   // k quarter: [kq*192, kq*192+192)

  const int L    = blockIdx.x;
  const int xcd  = L & 7;
  const int slot = L >> 3;
  const int col  = xcd + 8 * (slot & 3);   // = b*8 + es  (0..31)
  const int b    = col >> 3;
  const int es   = col & 7;
  const int d0   = (slot >> 2) * 4;        // block covers d0..d0+3

  // sumv = sum over ALL 768 vt
  float sumv = 0.f;
#pragma unroll
  for (int j = 0; j < 12; ++j) sumv += vt[lane + 64 * j];
#pragma unroll
  for (int s = 1; s < 64; s <<= 1) sumv += __shfl_xor(sumv, s, 64);

  // wave-uniform scalar sources (constant AS -> s_load_dwordx4)
  const float* pdr0 = pdm + (size_t)(b * DEC_SZ + d0 + dpair * 2) * H_SZ + kq * 192;
  cf4* pd0 = (cf4*)pdr0;
  cf4* pd1 = (cf4*)(pdr0 + H_SZ);
  cf4* vt4 = (cf4*)(vt + kq * 192);

  const f4r* pe4 = (const f4r*)peT + ((size_t)col * 192 + kq * 48) * 64 + lane;

  float t0 = 0.f, t1 = 0.f;
  f4r buf[8];
#pragma unroll
  for (int i = 0; i < 8; ++i) buf[i] = pe4[(size_t)i * 64];

#pragma unroll 8
  for (int c = 0; c < 48; ++c) {
    f4r cur = buf[c & 7];
    if (c + 8 < 48) buf[c & 7] = pe4[(size_t)(c + 8) * 64];
    f4r v4 = vt4[c];
    t0 = quad_acc(cur, pd0[c], v4, t0);
    t1 = quad_acc(cur, pd1[c], v4, t1);
  }

  __shared__ float tred[4][4][64];   // [kq][dloc][lane]
  tred[kq][dpair * 2 + 0][lane] = t0;
  tred[kq][dpair * 2 + 1][lane] = t1;
  __syncthreads();

  if (kq == 0) {
#pragma unroll
    for (int dd = 0; dd < 2; ++dd) {
      int dloc = dpair * 2 + dd;
      float t = tred[0][dloc][lane] + tred[1][dloc][lane] +
                tred[2][dloc][lane] + tred[3][dloc][lane];
      int d = d0 + dloc;
      const int e = es * 64 + lane;
      size_t idx = ((size_t)(b * DEC_SZ + d)) * ENC_SZ + e;
      float s = fmaf(-2.f, t, sumv);
      out[idx] = s + mask[idx];
      out[OUT_N + idx] = s;
    }
  }
}

extern "C" void kernel_launch(void* const* d_in, const int* in_sizes, int n_in,
                              void* d_out, int out_size, void* d_ws, size_t ws_size,
                              hipStream_t stream) {
  (void)in_sizes; (void)n_in; (void)out_size; (void)ws_size;
  const float* dec  = (const float*)d_in[0];  // (B, DEC, H)
  const float* enc  = (const float*)d_in[1];  // (B, ENC, H)
  const float* mask = (const float*)d_in[2];  // (B, DEC, ENC)
  const float* W1   = (const float*)d_in[3];  // (H, H) (k, n)
  const float* W2   = (const float*)d_in[4];  // (H, H) (k, n)
  const float* vt   = (const float*)d_in[5];  // (H,)
  float* out = (float*)d_out;

  // Workspace layout
  float* peT = (float*)d_ws;                            // tiled (B,8,192,64,4) 6.29 MB
  float* pdm = peT + (size_t)H_SZ * B_SZ * ENC_SZ;      // (B*DEC, H)   1.57 MB
  unsigned short* W1T = (unsigned short*)(pdm + (size_t)B_SZ * DEC_SZ * H_SZ);
  unsigned short* W2T = W1T + (size_t)H_SZ * H_SZ;

  transpose_w<<<dim3(12, 12, 2), 256, 0, stream>>>(W1, W2, W1T, W2T);
  gemm_both<<<dim3(240), 256, 0, stream>>>(W1T, enc, dec, W2T, peT, pdm);
  score_out<<<dim3(1024), 512, 0, stream>>>(peT, pdm, vt, mask, out);
}

// Round 12
// 122.246 us; speedup vs baseline: 1.2953x; 1.2953x over previous
//
#include <hip/hip_runtime.h>
#include <hip/hip_bf16.h>

#define B_SZ   4
#define DEC_SZ 128
#define ENC_SZ 512
#define H_SZ   768
#define OUT_N  (B_SZ * DEC_SZ * ENC_SZ)

typedef __attribute__((ext_vector_type(8))) short s8v;   // 8 bf16 (4 VGPRs)
typedef __attribute__((ext_vector_type(4))) float fvec4; // MFMA accumulator

// fp32 -> bf16, round-to-nearest-even
__device__ inline unsigned short f2bf(float x) {
  union { float f; unsigned u; } v; v.f = x;
  unsigned r = v.u + 0x7FFF + ((v.u >> 16) & 1);
  return (unsigned short)(r >> 16);
}

// load 8 k-contiguous elements as bf16x8 (converting if fp32 source)
__device__ inline s8v load8(const unsigned short* p) { return *(const s8v*)p; }
__device__ inline s8v load8(const float* p) {
  float4 a = ((const float4*)p)[0];
  float4 b = ((const float4*)p)[1];
  unsigned short r[8] = {f2bf(a.x), f2bf(a.y), f2bf(a.z), f2bf(a.w),
                         f2bf(b.x), f2bf(b.y), f2bf(b.z), f2bf(b.w)};
  return *(const s8v*)r;
}

// ---------------------------------------------------------------------------
// Prep: transpose W (768x768 fp32, (k,n)) -> WT bf16 (n,k). z selects W1/W2.
// ---------------------------------------------------------------------------
__global__ __launch_bounds__(256) void transpose_w(const float* __restrict__ W1,
                                                   const float* __restrict__ W2,
                                                   unsigned short* __restrict__ T1,
                                                   unsigned short* __restrict__ T2) {
  const float* W = blockIdx.z ? W2 : W1;
  unsigned short* T = blockIdx.z ? T2 : T1;
  __shared__ float tile[64][65];
  int c0 = blockIdx.x * 64;
  int r0 = blockIdx.y * 64;
  int tx = threadIdx.x & 63, ty = threadIdx.x >> 6;
#pragma unroll
  for (int i = 0; i < 16; ++i) {
    int r = ty + i * 4;
    tile[r][tx] = W[(size_t)(r0 + r) * H_SZ + c0 + tx];
  }
  __syncthreads();
#pragma unroll
  for (int i = 0; i < 16; ++i) {
    int c = ty + i * 4;
    T[(size_t)(c0 + c) * H_SZ + r0 + tx] = f2bf(tile[tx][c]);
  }
}

// ---------------------------------------------------------------------------
// MFMA NT GEMM body + exp2 epilogue, register-prefetch double-buffered.
// E[m][n] = exp2(C2 * sum_k A[m][k]*B[n][k]); A,B k-contiguous rows (len H).
// Tile 128x64, BK=32, 4 waves; fp32 operands converted to bf16 during staging.
// TILED: m = h, n = (b*ENC+e); float4 store to pe tile layout
//        ((b*8 + e/64)*192 + h/4)*64 + (e&63), component h&3.
// ---------------------------------------------------------------------------
template <bool TILED, typename TA, typename TB>
__device__ inline void gemm_body(const TA* __restrict__ A, const TB* __restrict__ B,
                                 float* __restrict__ C, int ldc, int bx, int by) {
  const int m0 = bx * 128;
  const int n0 = by * 64;

  __shared__ unsigned short As[128][40];  // pad 40: 80 B rows
  __shared__ unsigned short Bs[64][40];

  const int tid  = threadIdx.x;
  const int wave = tid >> 6;
  const int lane = tid & 63;
  const int l16  = lane & 15;
  const int quad = lane >> 4;
  const int wm   = wave * 32;

  int ar[2], ak[2];
#pragma unroll
  for (int i = 0; i < 2; ++i) {
    int seg = tid + 256 * i;
    ar[i] = seg >> 2; ak[i] = (seg & 3) * 8;
  }
  const int br = tid >> 2, bk = (tid & 3) * 8;

  fvec4 acc[2][4];
#pragma unroll
  for (int i = 0; i < 2; ++i)
#pragma unroll
    for (int j = 0; j < 4; ++j) acc[i][j] = (fvec4)0.f;

  s8v pa[2], pb;
#pragma unroll
  for (int i = 0; i < 2; ++i) pa[i] = load8(A + (size_t)(m0 + ar[i]) * H_SZ + ak[i]);
  pb = load8(B + (size_t)(n0 + br) * H_SZ + bk);

  for (int k0 = 0; k0 < H_SZ; k0 += 32) {
    __syncthreads();
#pragma unroll
    for (int i = 0; i < 2; ++i) *(s8v*)&As[ar[i]][ak[i]] = pa[i];
    *(s8v*)&Bs[br][bk] = pb;
    __syncthreads();

    if (k0 + 32 < H_SZ) {
#pragma unroll
      for (int i = 0; i < 2; ++i)
        pa[i] = load8(A + (size_t)(m0 + ar[i]) * H_SZ + k0 + 32 + ak[i]);
      pb = load8(B + (size_t)(n0 + br) * H_SZ + k0 + 32 + bk);
    }

    s8v af[2], bf[4];
#pragma unroll
    for (int i = 0; i < 2; ++i) af[i] = *(const s8v*)&As[wm + i * 16 + l16][quad * 8];
#pragma unroll
    for (int j = 0; j < 4; ++j) bf[j] = *(const s8v*)&Bs[j * 16 + l16][quad * 8];
#pragma unroll
    for (int i = 0; i < 2; ++i)
#pragma unroll
      for (int j = 0; j < 4; ++j)
        acc[i][j] = __builtin_amdgcn_mfma_f32_16x16x32_bf16(af[i], bf[j], acc[i][j], 0, 0, 0);
  }

  const float C2 = 2.885390082f;  // 2 * log2(e)
#pragma unroll
  for (int i = 0; i < 2; ++i) {
    int mbase = m0 + wm + i * 16 + quad * 4;  // C/D: row = quad*4 + reg, col = l16
#pragma unroll
    for (int j = 0; j < 4; ++j) {
      int n = n0 + j * 16 + l16;
      if (TILED) {
        float4 o;
        o.x = __builtin_amdgcn_exp2f(acc[i][j][0] * C2);
        o.y = __builtin_amdgcn_exp2f(acc[i][j][1] * C2);
        o.z = __builtin_amdgcn_exp2f(acc[i][j][2] * C2);
        o.w = __builtin_amdgcn_exp2f(acc[i][j][3] * C2);
        int bIdx = n >> 9, es = (n >> 6) & 7, el = n & 63;
        ((float4*)C)[((size_t)(bIdx * 8 + es) * 192 + (mbase >> 2)) * 64 + el] = o;
      } else {
#pragma unroll
        for (int r = 0; r < 4; ++r)
          C[(size_t)(mbase + r) * ldc + n] = __builtin_amdgcn_exp2f(acc[i][j][r] * C2);
      }
    }
  }
}

// Both GEMMs in one launch: blocks 0..191 -> pe GEMM, 192..239 -> pd GEMM.
__global__ __launch_bounds__(256) void gemm_both(const unsigned short* __restrict__ W1T,
                                                 const float* __restrict__ enc,
                                                 const float* __restrict__ dec,
                                                 const unsigned short* __restrict__ W2T,
                                                 float* __restrict__ peT,
                                                 float* __restrict__ pdm) {
  int bid = blockIdx.x;
  if (bid < 192) {
    gemm_body<true>(W1T, enc, peT, 0, bid % 6, bid / 6);
  } else {
    int r = bid - 192;
    gemm_body<false>(dec, W2T, pdm, H_SZ, r % 4, r / 4);
  }
}

// ---------------------------------------------------------------------------
// Fused score + mask + outputs. Quad-rcp batching (13 VALU + 1 rcp per 4 k),
// 4 d's per wave so the pe/vt loads + rotation amortize over 4 quads.
// Block 512 thr = 8 waves: wave = dg(2, 4 d's each) x kq(4, 48 quads each).
// Block covers 8 d x full k for one (b,es) column. 8KB LDS k-reduce.
// Grid = 512 XCD-swizzled blocks (32 cols x 16 dblocks) -> 4 waves/SIMD.
// pe layout: float4[(b*8+es)*192 + k/4][64lane]. Plain-pointer loads (R10
// style: AS4/s_load experiment regressed, R11).
// ---------------------------------------------------------------------------
__device__ inline float quad_acc(float4 cur, float4 p4, float4 v4, float t) {
  float a  = fmaf(cur.x, p4.x, 1.f);
  float bq = fmaf(cur.y, p4.y, 1.f);
  float cq = fmaf(cur.z, p4.z, 1.f);
  float dq = fmaf(cur.w, p4.w, 1.f);
  float ab = a * bq, cd = cq * dq;
  float n01 = fmaf(v4.x, bq, v4.y * a);
  float n23 = fmaf(v4.z, dq, v4.w * cq);
  float num = fmaf(n23, ab, n01 * cd);
  return fmaf(num, __builtin_amdgcn_rcpf(ab * cd), t);
}

__global__ __launch_bounds__(512) void score_out(const float* __restrict__ peT,
                                                 const float* __restrict__ pdm,
                                                 const float* __restrict__ vt,
                                                 const float* __restrict__ mask,
                                                 float* __restrict__ out) {
  const int tid  = threadIdx.x;
  const int lane = tid & 63;
  const int wave = __builtin_amdgcn_readfirstlane(tid >> 6);
  const int dg   = wave & 1;     // d-group within block (4 d's each)
  const int kq   = wave >> 1;    // k quarter: 48 quads

  const int L    = blockIdx.x;
  const int xcd  = L & 7;
  const int slot = L >> 3;
  const int col  = xcd + 8 * (slot & 3);   // = b*8 + es  (0..31)
  const int b    = col >> 3;
  const int es   = col & 7;
  const int d0   = (slot >> 2) * 8 + dg * 4;  // this wave's 4 d's

  // sumv = sum over ALL 768 vt
  float sumv = 0.f;
#pragma unroll
  for (int j = 0; j < 12; ++j) sumv += vt[lane + 64 * j];
#pragma unroll
  for (int s = 1; s < 64; s <<= 1) sumv += __shfl_xor(sumv, s, 64);

  // wave-uniform row pointers (plain pointers; compiler folds c*16 into imms)
  const float* pdr = pdm + (size_t)(b * DEC_SZ + d0) * H_SZ + kq * 192;
  const float* vth = vt + kq * 192;
  const float4* pe4 = (const float4*)peT + ((size_t)col * 192 + kq * 48) * 64 + lane;

  float t0 = 0.f, t1 = 0.f, t2 = 0.f, t3 = 0.f;
  float4 buf[8];
#pragma unroll
  for (int i = 0; i < 8; ++i) buf[i] = pe4[(size_t)i * 64];

#pragma unroll 8
  for (int c = 0; c < 48; ++c) {
    float4 cur = buf[c & 7];
    if (c + 8 < 48) buf[c & 7] = pe4[(size_t)(c + 8) * 64];
    float4 v4 = *(const float4*)(vth + c * 4);
    t0 = quad_acc(cur, *(const float4*)(pdr + c * 4), v4, t0);
    t1 = quad_acc(cur, *(const float4*)(pdr + H_SZ + c * 4), v4, t1);
    t2 = quad_acc(cur, *(const float4*)(pdr + 2 * H_SZ + c * 4), v4, t2);
    t3 = quad_acc(cur, *(const float4*)(pdr + 3 * H_SZ + c * 4), v4, t3);
  }

  __shared__ float tred[4][8][64];   // [kq][dloc][lane], 8 KB
  {
    int dl = dg * 4;
    tred[kq][dl + 0][lane] = t0;
    tred[kq][dl + 1][lane] = t1;
    tred[kq][dl + 2][lane] = t2;
    tred[kq][dl + 3][lane] = t3;
  }
  __syncthreads();

  if (kq == 0) {
    const int e = es * 64 + lane;
#pragma unroll
    for (int j = 0; j < 4; ++j) {
      int dl = dg * 4 + j;
      float t = tred[0][dl][lane] + tred[1][dl][lane] +
                tred[2][dl][lane] + tred[3][dl][lane];
      int d = (slot >> 2) * 8 + dl;
      size_t idx = ((size_t)(b * DEC_SZ + d)) * ENC_SZ + e;
      float s = fmaf(-2.f, t, sumv);
      out[idx] = s + mask[idx];
      out[OUT_N + idx] = s;
    }
  }
}

extern "C" void kernel_launch(void* const* d_in, const int* in_sizes, int n_in,
                              void* d_out, int out_size, void* d_ws, size_t ws_size,
                              hipStream_t stream) {
  (void)in_sizes; (void)n_in; (void)out_size; (void)ws_size;
  const float* dec  = (const float*)d_in[0];  // (B, DEC, H)
  const float* enc  = (const float*)d_in[1];  // (B, ENC, H)
  const float* mask = (const float*)d_in[2];  // (B, DEC, ENC)
  const float* W1   = (const float*)d_in[3];  // (H, H) (k, n)
  const float* W2   = (const float*)d_in[4];  // (H, H) (k, n)
  const float* vt   = (const float*)d_in[5];  // (H,)
  float* out = (float*)d_out;

  // Workspace layout
  float* peT = (float*)d_ws;                            // tiled (B,8,192,64,4) 6.29 MB
  float* pdm = peT + (size_t)H_SZ * B_SZ * ENC_SZ;      // (B*DEC, H)   1.57 MB
  unsigned short* W1T = (unsigned short*)(pdm + (size_t)B_SZ * DEC_SZ * H_SZ);
  unsigned short* W2T = W1T + (size_t)H_SZ * H_SZ;

  transpose_w<<<dim3(12, 12, 2), 256, 0, stream>>>(W1, W2, W1T, W2T);
  gemm_both<<<dim3(240), 256, 0, stream>>>(W1T, enc, dec, W2T, peT, pdm);
  score_out<<<dim3(512), 512, 0, stream>>>(peT, pdm, vt, mask, out);
}